// Round 21
// baseline (161.204 us; speedup 1.0000x reference)
//
#include <hip/hip_runtime.h>

// Trilinear feature-grid interpolation, v16 = v14 (129.5us best) with the
// gather split by x-half: 4 resident blocks/CU (extends round-19's
// 1->2-block win). Front-end (NB=8192 bins, float4 records) unchanged.
// grid layout: [R][R][R][3] = [z][y][x][c], R=256, fp32 (192 MB).
//
// Gather block = (bin, xh): stages 9-row x 129-cell (incl. x-halo) layers
// (97 f4/row, 14.0 KB/layer, 2-slot window = 27.9 KB -> 4 blocks/CU at
// 512 thr). Both halves scan the bin's point list (coalesced) and
// predicate on xl>>7 == xh. Half-x geometry verbatim from v10 (verified).

#define NB     8192
#define CAP    512u
#define GBLK   512
#define CHF4   97                 // f4 per row chunk (129 cells + pad)
#define LAYF4  873                // 9 rows x 97 f4
#define LAYF   (LAYF4 * 4)        // 3492 floats = 13968 B
#define GRIDF4 12582912           // total float4 in grid

// ws layout: binned[8192*512] float4 = 64MB, then cur[8192]
#define CUR_OFF   67108864u
#define NEEDED    (67108864u + 32768u)

typedef float f4v __attribute__((ext_vector_type(4)));
typedef float f2v __attribute__((ext_vector_type(2)));
typedef f4v f4u __attribute__((aligned(8)));
typedef f2v f2u __attribute__((aligned(8)));

__device__ __forceinline__ void cell_of(float p, int& l, float& t) {
    float s = p * 255.0f;
    int v = (int)floorf(s);
    v = v < 0 ? 0 : (v > 254 ? 254 : v);
    l = v;
    t = s - (float)v;
}

// fine bin: K = zl*32 + (yl>>3)  (full x, 8 y-cells, 1 z-cell)
__device__ __forceinline__ int fine_bin3(float px, float py, float pz) {
    int xl, yl, zl; float tx, ty, tz;
    cell_of(px, xl, tx);
    cell_of(py, yl, ty);
    cell_of(pz, zl, tz);
    return (zl << 5) | (yl >> 3);
}

__device__ __forceinline__ void direct_lerp(const float* __restrict__ grid,
                                            float* __restrict__ out, int i,
                                            int xl, int yl, int zl,
                                            float tx, float ty, float tz) {
    int b00 = (zl * 65536 + yl * 256 + xl) * 3;
    int b01 = b00 + 768, b10 = b00 + 196608, b11 = b10 + 768;
    float s00[6], s01[6], s10[6], s11[6];
#pragma unroll
    for (int k = 0; k < 6; ++k) s00[k] = grid[b00 + k];
#pragma unroll
    for (int k = 0; k < 6; ++k) s01[k] = grid[b01 + k];
#pragma unroll
    for (int k = 0; k < 6; ++k) s10[k] = grid[b10 + k];
#pragma unroll
    for (int k = 0; k < 6; ++k) s11[k] = grid[b11 + k];
#pragma unroll
    for (int c = 0; c < 3; ++c) {
        float c00 = s00[c] * (1.0f - tx) + s00[c + 3] * tx;
        float c01 = s01[c] * (1.0f - tx) + s01[c + 3] * tx;
        float c10 = s10[c] * (1.0f - tx) + s10[c + 3] * tx;
        float c11 = s11[c] * (1.0f - tx) + s11[c + 3] * tx;
        float c0 = c00 * (1.0f - ty) + c01 * ty;
        float c1 = c10 * (1.0f - ty) + c11 * ty;
        out[3 * i + c] = c0 * (1.0f - tz) + c1 * tz;
    }
}

// ---------------- pass 0: init cursors to region bases ----------------
__global__ __launch_bounds__(1024) void k_init(unsigned* __restrict__ cur) {
    int i = blockIdx.x * 1024 + threadIdx.x;
    if (i < NB) cur[i] = (unsigned)i * CAP;
}

// ---------------- pass 1: block-aggregated scatter (2 pts/thread) ----------------
__global__ __launch_bounds__(1024) void k_scatter(const float* __restrict__ inp,
                                                  const float* __restrict__ grid,
                                                  float4* __restrict__ binned,
                                                  unsigned* __restrict__ cur,
                                                  float* __restrict__ out, int n) {
    __shared__ unsigned cnt[NB];
    __shared__ unsigned base[NB];
    int t = threadIdx.x;
    int P = n >> 1;
    int stride = gridDim.x * 1024;
    int iters = (P + stride - 1) / stride;

    if ((n & 1) && blockIdx.x == 0 && t == 0) {
        int i = n - 1;
        float px = inp[3 * i], py = inp[3 * i + 1], pz = inp[3 * i + 2];
        int b = fine_bin3(px, py, pz);
        unsigned r = atomicAdd(&cur[b], 1u);
        if (r - (unsigned)b * CAP < CAP) {
            float4 v; v.x = px; v.y = py; v.z = pz; v.w = __uint_as_float((unsigned)i);
            binned[r] = v;
        } else {
            int xl, yl, zl; float tx, ty, tz;
            cell_of(px, xl, tx); cell_of(py, yl, ty); cell_of(pz, zl, tz);
            direct_lerp(grid, out, i, xl, yl, zl, tx, ty, tz);
        }
    }

    for (int it = 0; it < iters; ++it) {
        int pr = it * stride + blockIdx.x * 1024 + t;
        for (int k = t; k < NB; k += 1024) cnt[k] = 0;
        __syncthreads();
        int b0 = 0, b1 = 0; unsigned r0 = 0, r1 = 0;
        float4 p0, p1;
        bool valid = (pr < P);
        if (valid) {
            f4v a = *(const f4u*)(inp + 6 * pr);
            f2v b = *(const f2u*)(inp + 6 * pr + 4);
            p0.x = a.x; p0.y = a.y; p0.z = a.z;
            p0.w = __uint_as_float((unsigned)(2 * pr));
            p1.x = a.w; p1.y = b.x; p1.z = b.y;
            p1.w = __uint_as_float((unsigned)(2 * pr + 1));
            b0 = fine_bin3(p0.x, p0.y, p0.z);
            b1 = fine_bin3(p1.x, p1.y, p1.z);
            r0 = atomicAdd(&cnt[b0], 1u);
            r1 = atomicAdd(&cnt[b1], 1u);
        }
        __syncthreads();
        for (int k = t; k < NB; k += 1024)
            if (cnt[k]) base[k] = atomicAdd(&cur[k], cnt[k]);
        __syncthreads();
        if (valid) {
            unsigned s0 = base[b0] + r0;
            unsigned s1 = base[b1] + r1;
            if (s0 - (unsigned)b0 * CAP < CAP) binned[s0] = p0;
            else {
                int xl, yl, zl; float tx, ty, tz;
                cell_of(p0.x, xl, tx); cell_of(p0.y, yl, ty); cell_of(p0.z, zl, tz);
                direct_lerp(grid, out, 2 * pr, xl, yl, zl, tx, ty, tz);
            }
            if (s1 - (unsigned)b1 * CAP < CAP) binned[s1] = p1;
            else {
                int xl, yl, zl; float tx, ty, tz;
                cell_of(p1.x, xl, tx); cell_of(p1.y, yl, ty); cell_of(p1.z, zl, tz);
                direct_lerp(grid, out, 2 * pr + 1, xl, yl, zl, tx, ty, tz);
            }
        }
        __syncthreads();
    }
}

// ---------------- pass 2: z-walk gather, reg-staged 2-slot, half-x blocks ----------------
// Layer L of block (bin,xh) = 9 rows of 97 f4 ([z0+L][y0+r][x0..x0+129)).
// 512 threads: thread t covers f4 index t, and t+512 (t < 361).
#define LOADL(L)                                                        \
    do {                                                                \
        int zg = z0 + (L); if (zg > 255) zg = 255;                      \
        size_t b4 = (size_t)zg * 49152 + (size_t)y0 * 192 + (size_t)xq96; \
        {                                                               \
            int r_ = t / CHF4, j_ = t - r_ * CHF4;                      \
            size_t s0_ = b4 + (size_t)r_ * 192 + (size_t)j_;            \
            if (s0_ > (size_t)(GRIDF4 - 1)) s0_ = (size_t)(GRIDF4 - 1); \
            R0 = *(const f4u*)(grid + s0_ * 4);                         \
        }                                                               \
        if (t < LAYF4 - 512) {                                          \
            int u_ = t + 512;                                           \
            int r_ = u_ / CHF4, j_ = u_ - r_ * CHF4;                    \
            size_t s1_ = b4 + (size_t)r_ * 192 + (size_t)j_;            \
            if (s1_ > (size_t)(GRIDF4 - 1)) s1_ = (size_t)(GRIDF4 - 1); \
            R1 = *(const f4u*)(grid + s1_ * 4);                         \
        }                                                               \
    } while (0)

#define WRITEL(slot_)                                                   \
    do {                                                                \
        float* dst = &slab[(slot_) * LAYF];                             \
        *(f4v*)&dst[(size_t)t * 4] = R0;                                \
        if (t < LAYF4 - 512) *(f4v*)&dst[(size_t)(t + 512) * 4] = R1;   \
    } while (0)

__global__ __launch_bounds__(GBLK) void k_gather(const float4* __restrict__ binned,
                                                 const float* __restrict__ grid,
                                                 const unsigned* __restrict__ cur,
                                                 float* __restrict__ out) {
    __shared__ __align__(16) float slab[2 * LAYF];   // 27936 B -> 4 blocks/CU
    int t = threadIdx.x;
    // 1024 blocks; XCD-chunked (bijective on [0,1024)): XCD k owns a
    // contiguous col range -> both halves of a bin + z/y-neighbors share L2.
    int col = ((blockIdx.x & 7) << 7) | (blockIdx.x >> 3);
    int bin = col >> 1;
    int xh  = col & 1;
    int zb = bin >> 5;            // 16 z-segments of 16 cells
    int yb = bin & 31;            // 32 y-bins of 8 cells
    int z0 = zb << 4;
    int y0 = yb << 3;
    int x0 = xh << 7;
    int xq96 = xh * 96;           // x offset in f4 units (128*3/4)

    f4v R0, R1;

    LOADL(0); WRITEL(0);          // layer 0 -> slot 0 (ds_write waits vmcnt)
    LOADL(1);                     // layer 1 in regs

    for (int zc = 0; zc < 16; ++zc) {
        WRITEL((zc + 1) & 1);     // layer zc+1 (vmcnt wait auto-inserted)
        __syncthreads();
        if (zc <= 14) LOADL(zc + 2);   // flies under this step's compute
                                       // (zc<=14 stages z0+16: round-15 bug class, audited)

        int sA = (zc & 1) * LAYF;
        int sB = ((zc + 1) & 1) * LAYF;

        int K = ((z0 + zc) << 5) | yb;
        unsigned start = (unsigned)K * CAP;
        unsigned count = cur[K] - start;
        if (count > CAP) count = CAP;

        for (unsigned p = (unsigned)t; p < count; p += (unsigned)GBLK) {
            float4 v = binned[start + p];
            unsigned idx = __float_as_uint(v.w);

            int xl, yl, zl; float tx, ty, tz;
            cell_of(v.x, xl, tx);
            cell_of(v.y, yl, ty);
            cell_of(v.z, zl, tz);
            if ((xl >> 7) != xh) continue;     // other half's block handles it

            int row = yl - y0;                 // 0..7
            int xc  = xl - x0;                 // 0..127

            int o00 = sA + row * 388 + xc * 3;
            int o01 = o00 + 388;
            int o10 = sB + row * 388 + xc * 3;
            int o11 = o10 + 388;

#define SEG_READ(b, s)                                   \
            do {                                         \
                int e_ = (b) & ~1;                       \
                bool d_ = ((b) & 1) != 0;                \
                f2v q0 = *(const f2u*)(&slab[e_]);       \
                f2v q1 = *(const f2u*)(&slab[e_ + 2]);   \
                f2v q2 = *(const f2u*)(&slab[e_ + 4]);   \
                f2v q3 = *(const f2u*)(&slab[e_ + 6]);   \
                s[0] = d_ ? q0.y : q0.x;                 \
                s[1] = d_ ? q1.x : q0.y;                 \
                s[2] = d_ ? q1.y : q1.x;                 \
                s[3] = d_ ? q2.x : q1.y;                 \
                s[4] = d_ ? q2.y : q2.x;                 \
                s[5] = d_ ? q3.x : q2.y;                 \
            } while (0)

            float s00[6], s01[6], s10[6], s11[6];
            SEG_READ(o00, s00);   // (zl,   yl)
            SEG_READ(o01, s01);   // (zl,   yl+1)
            SEG_READ(o10, s10);   // (zl+1, yl)
            SEG_READ(o11, s11);   // (zl+1, yl+1)
#undef SEG_READ

            float o[3];
#pragma unroll
            for (int c = 0; c < 3; ++c) {
                float c00 = s00[c] * (1.0f - tx) + s00[c + 3] * tx;
                float c01 = s01[c] * (1.0f - tx) + s01[c + 3] * tx;
                float c10 = s10[c] * (1.0f - tx) + s10[c + 3] * tx;
                float c11 = s11[c] * (1.0f - tx) + s11[c + 3] * tx;
                float c0 = c00 * (1.0f - ty) + c01 * ty;
                float c1 = c10 * (1.0f - ty) + c11 * ty;
                o[c] = c0 * (1.0f - tz) + c1 * tz;
            }
            float3 w; w.x = o[0]; w.y = o[1]; w.z = o[2];
            *(float3*)(out + 3 * (size_t)idx) = w;
        }

        __syncthreads();          // fence slab readers before next WRITEL
    }
}

// ---------------- fallback: direct ----------------
__global__ __launch_bounds__(256) void k_direct(const float* __restrict__ inp,
                                                const float* __restrict__ grid,
                                                float* __restrict__ out, int n) {
    int i = blockIdx.x * blockDim.x + threadIdx.x;
    if (i >= n) return;
    int xl, yl, zl; float tx, ty, tz;
    cell_of(inp[3 * i + 0], xl, tx);
    cell_of(inp[3 * i + 1], yl, ty);
    cell_of(inp[3 * i + 2], zl, tz);
    direct_lerp(grid, out, i, xl, yl, zl, tx, ty, tz);
}

extern "C" void kernel_launch(void* const* d_in, const int* in_sizes, int n_in,
                              void* d_out, int out_size, void* d_ws, size_t ws_size,
                              hipStream_t stream) {
    const float* inp  = (const float*)d_in[0];  // [N][3]
    const float* grid = (const float*)d_in[1];  // [256][256][256][3]
    float* out = (float*)d_out;                 // [N][3]
    int n = in_sizes[0] / 3;

    if (ws_size < (size_t)NEEDED) {
        int blocks = (n + 255) / 256;
        k_direct<<<blocks, 256, 0, stream>>>(inp, grid, out, n);
        return;
    }

    char* ws = (char*)d_ws;
    float4*   binned = (float4*)ws;
    unsigned* cur    = (unsigned*)(ws + CUR_OFF);

    k_init   <<<8,    1024, 0, stream>>>(cur);
    k_scatter<<<512,  1024, 0, stream>>>(inp, grid, binned, cur, out, n);
    k_gather <<<1024, GBLK, 0, stream>>>(binned, grid, cur, out);
}

// Round 22
// 129.057 us; speedup vs baseline: 1.2491x; 1.2491x over previous
//
#include <hip/hip_runtime.h>

// Trilinear feature-grid interpolation — FINAL (v14, measured 129.5us).
// grid layout: [R][R][R][3] = [z][y][x][c], R=256, fp32 (192 MB).
//
// Pipeline: k_init (cursors) -> k_scatter (block-aggregated LDS-count
// binning into 8192 fixed-cap bins keyed (zl, yl>>3)) -> k_gather
// (per-bin z-walk; reg-staged 2-slot rolling LDS window of contiguous
// 27.6KB y-slab layers; 55.3KB LDS -> 2 resident blocks/CU).
// Campaign results (rounds 1-21, 12 structural hypotheses): reg-staging
// (+10%) and 2-blocks/CU (+3%) were the only real gather levers;
// burst shape, wave autonomy, store eviction, compression, >2 blocks/CU
// all null/negative. Gather service rate saturates at ~2.4 TB/s for this
// footprint; remaining gap to BW floor is the per-step vmcnt/barrier
// drain (m97-class structural wall).

#define NB     8192
#define CAP    512u
#define GBLK   512
#define LAYERF4 1728              // float4 per layer (9 rows x 192 f4, contiguous)
#define LAYERF  6912              // floats per layer (27648 B)
#define GRIDF4  12582912          // total float4 in grid

// ws layout: binned[8192*512] float4 = 64MB, then cur[8192]
#define CUR_OFF   67108864u
#define NEEDED    (67108864u + 32768u)

typedef float f4v __attribute__((ext_vector_type(4)));
typedef float f2v __attribute__((ext_vector_type(2)));
typedef f4v f4u __attribute__((aligned(8)));
typedef f2v f2u __attribute__((aligned(8)));

__device__ __forceinline__ void cell_of(float p, int& l, float& t) {
    float s = p * 255.0f;
    int v = (int)floorf(s);
    v = v < 0 ? 0 : (v > 254 ? 254 : v);
    l = v;
    t = s - (float)v;
}

// fine bin: K = zl*32 + (yl>>3)  (full x, 8 y-cells, 1 z-cell)
__device__ __forceinline__ int fine_bin3(float px, float py, float pz) {
    int xl, yl, zl; float tx, ty, tz;
    cell_of(px, xl, tx);
    cell_of(py, yl, ty);
    cell_of(pz, zl, tz);
    return (zl << 5) | (yl >> 3);
}

__device__ __forceinline__ void direct_lerp(const float* __restrict__ grid,
                                            float* __restrict__ out, int i,
                                            int xl, int yl, int zl,
                                            float tx, float ty, float tz) {
    int b00 = (zl * 65536 + yl * 256 + xl) * 3;
    int b01 = b00 + 768, b10 = b00 + 196608, b11 = b10 + 768;
    float s00[6], s01[6], s10[6], s11[6];
#pragma unroll
    for (int k = 0; k < 6; ++k) s00[k] = grid[b00 + k];
#pragma unroll
    for (int k = 0; k < 6; ++k) s01[k] = grid[b01 + k];
#pragma unroll
    for (int k = 0; k < 6; ++k) s10[k] = grid[b10 + k];
#pragma unroll
    for (int k = 0; k < 6; ++k) s11[k] = grid[b11 + k];
#pragma unroll
    for (int c = 0; c < 3; ++c) {
        float c00 = s00[c] * (1.0f - tx) + s00[c + 3] * tx;
        float c01 = s01[c] * (1.0f - tx) + s01[c + 3] * tx;
        float c10 = s10[c] * (1.0f - tx) + s10[c + 3] * tx;
        float c11 = s11[c] * (1.0f - tx) + s11[c + 3] * tx;
        float c0 = c00 * (1.0f - ty) + c01 * ty;
        float c1 = c10 * (1.0f - ty) + c11 * ty;
        out[3 * i + c] = c0 * (1.0f - tz) + c1 * tz;
    }
}

// ---------------- pass 0: init cursors to region bases ----------------
__global__ __launch_bounds__(1024) void k_init(unsigned* __restrict__ cur) {
    int i = blockIdx.x * 1024 + threadIdx.x;
    if (i < NB) cur[i] = (unsigned)i * CAP;
}

// ---------------- pass 1: block-aggregated scatter (2 pts/thread) ----------------
__global__ __launch_bounds__(1024) void k_scatter(const float* __restrict__ inp,
                                                  const float* __restrict__ grid,
                                                  float4* __restrict__ binned,
                                                  unsigned* __restrict__ cur,
                                                  float* __restrict__ out, int n) {
    __shared__ unsigned cnt[NB];
    __shared__ unsigned base[NB];
    int t = threadIdx.x;
    int P = n >> 1;
    int stride = gridDim.x * 1024;
    int iters = (P + stride - 1) / stride;

    if ((n & 1) && blockIdx.x == 0 && t == 0) {
        int i = n - 1;
        float px = inp[3 * i], py = inp[3 * i + 1], pz = inp[3 * i + 2];
        int b = fine_bin3(px, py, pz);
        unsigned r = atomicAdd(&cur[b], 1u);
        if (r - (unsigned)b * CAP < CAP) {
            float4 v; v.x = px; v.y = py; v.z = pz; v.w = __uint_as_float((unsigned)i);
            binned[r] = v;
        } else {
            int xl, yl, zl; float tx, ty, tz;
            cell_of(px, xl, tx); cell_of(py, yl, ty); cell_of(pz, zl, tz);
            direct_lerp(grid, out, i, xl, yl, zl, tx, ty, tz);
        }
    }

    for (int it = 0; it < iters; ++it) {
        int pr = it * stride + blockIdx.x * 1024 + t;
        for (int k = t; k < NB; k += 1024) cnt[k] = 0;
        __syncthreads();
        int b0 = 0, b1 = 0; unsigned r0 = 0, r1 = 0;
        float4 p0, p1;
        bool valid = (pr < P);
        if (valid) {
            f4v a = *(const f4u*)(inp + 6 * pr);
            f2v b = *(const f2u*)(inp + 6 * pr + 4);
            p0.x = a.x; p0.y = a.y; p0.z = a.z;
            p0.w = __uint_as_float((unsigned)(2 * pr));
            p1.x = a.w; p1.y = b.x; p1.z = b.y;
            p1.w = __uint_as_float((unsigned)(2 * pr + 1));
            b0 = fine_bin3(p0.x, p0.y, p0.z);
            b1 = fine_bin3(p1.x, p1.y, p1.z);
            r0 = atomicAdd(&cnt[b0], 1u);
            r1 = atomicAdd(&cnt[b1], 1u);
        }
        __syncthreads();
        for (int k = t; k < NB; k += 1024)
            if (cnt[k]) base[k] = atomicAdd(&cur[k], cnt[k]);
        __syncthreads();
        if (valid) {
            unsigned s0 = base[b0] + r0;
            unsigned s1 = base[b1] + r1;
            if (s0 - (unsigned)b0 * CAP < CAP) binned[s0] = p0;
            else {
                int xl, yl, zl; float tx, ty, tz;
                cell_of(p0.x, xl, tx); cell_of(p0.y, yl, ty); cell_of(p0.z, zl, tz);
                direct_lerp(grid, out, 2 * pr, xl, yl, zl, tx, ty, tz);
            }
            if (s1 - (unsigned)b1 * CAP < CAP) binned[s1] = p1;
            else {
                int xl, yl, zl; float tx, ty, tz;
                cell_of(p1.x, xl, tx); cell_of(p1.y, yl, ty); cell_of(p1.z, zl, tz);
                direct_lerp(grid, out, 2 * pr + 1, xl, yl, zl, tx, ty, tz);
            }
        }
        __syncthreads();
    }
}

// ---------------- pass 2: z-walk gather, reg-staged 2-slot window ----------------
// Layer L of this block = grid[z0+L][y0..y0+9)][*] : 1728 contiguous float4.
// 512 threads: thread t covers f4 indices t, t+512, t+1024, (t<192: t+1536).
#define LOADL(L)                                                        \
    do {                                                                \
        int zg = z0 + (L); if (zg > 255) zg = 255;                      \
        size_t b4 = (size_t)zg * 49152 + (size_t)y0 * 192;              \
        size_t u0 = b4 + (size_t)t;                                     \
        size_t u1 = b4 + 512 + (size_t)t;                               \
        size_t u2 = b4 + 1024 + (size_t)t;                              \
        if (u0 > (size_t)(GRIDF4 - 1)) u0 = (size_t)(GRIDF4 - 1);       \
        if (u1 > (size_t)(GRIDF4 - 1)) u1 = (size_t)(GRIDF4 - 1);       \
        if (u2 > (size_t)(GRIDF4 - 1)) u2 = (size_t)(GRIDF4 - 1);       \
        R0 = *(const f4u*)(grid + u0 * 4);                              \
        R1 = *(const f4u*)(grid + u1 * 4);                              \
        R2 = *(const f4u*)(grid + u2 * 4);                              \
        if (t < LAYERF4 - 1536) {                                       \
            size_t u3 = b4 + 1536 + (size_t)t;                          \
            if (u3 > (size_t)(GRIDF4 - 1)) u3 = (size_t)(GRIDF4 - 1);   \
            R3 = *(const f4u*)(grid + u3 * 4);                          \
        }                                                               \
    } while (0)

#define WRITEL(slot_)                                                   \
    do {                                                                \
        float* dst = &slab[(slot_) * LAYERF];                           \
        *(f4v*)&dst[(size_t)t * 4] = R0;                                \
        *(f4v*)&dst[(size_t)(t + 512) * 4] = R1;                        \
        *(f4v*)&dst[(size_t)(t + 1024) * 4] = R2;                       \
        if (t < LAYERF4 - 1536) *(f4v*)&dst[(size_t)(t + 1536) * 4] = R3; \
    } while (0)

__global__ __launch_bounds__(GBLK) void k_gather(const float4* __restrict__ binned,
                                                 const float* __restrict__ grid,
                                                 const unsigned* __restrict__ cur,
                                                 float* __restrict__ out) {
    __shared__ __align__(16) float slab[2 * LAYERF];   // 55296 B -> 2 blocks/CU
    int t = threadIdx.x;
    // 512 blocks; XCD-chunked: XCD k owns bins [64k, 64k+64) = 2 contiguous
    // z-segments x all y (halo layers shared within the XCD's L2).
    int bin = ((blockIdx.x & 7) << 6) | (blockIdx.x >> 3);   // bijective [0,512)
    int zb = bin >> 5;            // 16 z-segments of 16 cells
    int yb = bin & 31;            // 32 y-bins of 8 cells
    int z0 = zb << 4;
    int y0 = yb << 3;

    f4v R0, R1, R2, R3;

    LOADL(0); WRITEL(0);          // layer 0 -> slot 0 (ds_write waits vmcnt)
    LOADL(1);                     // layer 1 in regs

    for (int zc = 0; zc < 16; ++zc) {
        // Write layer zc+1 (in regs) into slot (zc+1)&1. Previous content
        // (layer zc-1) was last read at step zc-1, fenced by its trailing
        // barrier. Compiler inserts the vmcnt wait for the LOADL regs.
        WRITEL((zc + 1) & 1);
        __syncthreads();          // ds_writes visible to all waves

        // Issue layer zc+2's loads; they fly under this step's compute and
        // must land before next step's WRITEL. zc<=14 stages z0+16 (upper
        // layer of step 15) — the round-15 bug class, guard audited.
        if (zc <= 14) LOADL(zc + 2);

        int sA = (zc & 1) * LAYERF;
        int sB = ((zc + 1) & 1) * LAYERF;

        int K = ((z0 + zc) << 5) | yb;
        unsigned start = (unsigned)K * CAP;
        unsigned count = cur[K] - start;
        if (count > CAP) count = CAP;

        for (unsigned p = (unsigned)t; p < count; p += (unsigned)GBLK) {
            float4 v = binned[start + p];
            unsigned idx = __float_as_uint(v.w);

            int xl, yl, zl; float tx, ty, tz;
            cell_of(v.x, xl, tx);
            cell_of(v.y, yl, ty);
            cell_of(v.z, zl, tz);
            int row = yl - y0;                 // 0..7

            int o00 = sA + row * 768 + xl * 3;
            int o01 = o00 + 768;
            int o10 = sB + row * 768 + xl * 3;
            int o11 = o10 + 768;

#define SEG_READ(b, s)                                   \
            do {                                         \
                int e_ = (b) & ~1;                       \
                bool d_ = ((b) & 1) != 0;                \
                f2v q0 = *(const f2u*)(&slab[e_]);       \
                f2v q1 = *(const f2u*)(&slab[e_ + 2]);   \
                f2v q2 = *(const f2u*)(&slab[e_ + 4]);   \
                f2v q3 = *(const f2u*)(&slab[e_ + 6]);   \
                s[0] = d_ ? q0.y : q0.x;                 \
                s[1] = d_ ? q1.x : q0.y;                 \
                s[2] = d_ ? q1.y : q1.x;                 \
                s[3] = d_ ? q2.x : q1.y;                 \
                s[4] = d_ ? q2.y : q2.x;                 \
                s[5] = d_ ? q3.x : q2.y;                 \
            } while (0)

            float s00[6], s01[6], s10[6], s11[6];
            SEG_READ(o00, s00);   // (zl,   yl)
            SEG_READ(o01, s01);   // (zl,   yl+1)
            SEG_READ(o10, s10);   // (zl+1, yl)
            SEG_READ(o11, s11);   // (zl+1, yl+1)
#undef SEG_READ

            float o[3];
#pragma unroll
            for (int c = 0; c < 3; ++c) {
                float c00 = s00[c] * (1.0f - tx) + s00[c + 3] * tx;
                float c01 = s01[c] * (1.0f - tx) + s01[c + 3] * tx;
                float c10 = s10[c] * (1.0f - tx) + s10[c + 3] * tx;
                float c11 = s11[c] * (1.0f - tx) + s11[c + 3] * tx;
                float c0 = c00 * (1.0f - ty) + c01 * ty;
                float c1 = c10 * (1.0f - ty) + c11 * ty;
                o[c] = c0 * (1.0f - tz) + c1 * tz;
            }
            float3 w; w.x = o[0]; w.y = o[1]; w.z = o[2];
            *(float3*)(out + 3 * (size_t)idx) = w;
        }

        // Fence this step's slab readers before next step's WRITEL overwrites
        // slot zc&1.
        __syncthreads();
    }
}

// ---------------- fallback: direct ----------------
__global__ __launch_bounds__(256) void k_direct(const float* __restrict__ inp,
                                                const float* __restrict__ grid,
                                                float* __restrict__ out, int n) {
    int i = blockIdx.x * blockDim.x + threadIdx.x;
    if (i >= n) return;
    int xl, yl, zl; float tx, ty, tz;
    cell_of(inp[3 * i + 0], xl, tx);
    cell_of(inp[3 * i + 1], yl, ty);
    cell_of(inp[3 * i + 2], zl, tz);
    direct_lerp(grid, out, i, xl, yl, zl, tx, ty, tz);
}

extern "C" void kernel_launch(void* const* d_in, const int* in_sizes, int n_in,
                              void* d_out, int out_size, void* d_ws, size_t ws_size,
                              hipStream_t stream) {
    const float* inp  = (const float*)d_in[0];  // [N][3]
    const float* grid = (const float*)d_in[1];  // [256][256][256][3]
    float* out = (float*)d_out;                 // [N][3]
    int n = in_sizes[0] / 3;

    if (ws_size < (size_t)NEEDED) {
        int blocks = (n + 255) / 256;
        k_direct<<<blocks, 256, 0, stream>>>(inp, grid, out, n);
        return;
    }

    char* ws = (char*)d_ws;
    float4*   binned = (float4*)ws;
    unsigned* cur    = (unsigned*)(ws + CUR_OFF);

    k_init   <<<8,   1024, 0, stream>>>(cur);
    k_scatter<<<512, 1024, 0, stream>>>(inp, grid, binned, cur, out, n);
    k_gather <<<512, GBLK, 0, stream>>>(binned, grid, cur, out);
}